// Round 1
// baseline (392.795 us; speedup 1.0000x reference)
//
#include <hip/hip_runtime.h>
#include <hip/hip_bf16.h>
#include <cstdint>

// Workspace layout (bytes):
//   [0,        8388608)  xb   : x as bf16 [4096][1024]   (aliased later as ao)
//   [8388608, 14680064)  wqkvT: w_qkv^T bf16 [3072][1024]
//   [14680064,16777216)  wprojT: w_proj^T bf16 [1024][1024]
//   [16777216,25165824)  qb   : q (rope'd, *SCALE*log2e) bf16 [16][4096][64]
//   [25165824,33554432)  kb   : k (rope'd) bf16 [16][4096][64]
//   [33554432,41943040)  vT   : v^T bf16 [16][64][4096]
//   ao (attention out bf16 [4096][1024]) aliases xb.

#define TOK 4096
#define DIM_ 1024
#define NHEAD 16
#define HDIM 64
#define N3 3072
#define SCALE_LOG2E 0.18033688011112042f  // (1/8) * log2(e)

typedef __bf16 bf16_t;
typedef bf16_t bf16x8 __attribute__((ext_vector_type(8)));
typedef float floatx4 __attribute__((ext_vector_type(4)));

__device__ __forceinline__ void async_ld16(const bf16_t* g, bf16_t* l) {
  __builtin_amdgcn_global_load_lds(
      (const __attribute__((address_space(1))) void*)(g),
      (__attribute__((address_space(3))) void*)(l), 16, 0, 0);
}

// ---------------- convert x -> bf16 ----------------
__global__ __launch_bounds__(256) void k_cvt(const float* __restrict__ in,
                                             bf16_t* __restrict__ out, int n4) {
  int i = blockIdx.x * 256 + threadIdx.x;
  if (i < n4) {
    float4 v = ((const float4*)in)[i];
    union { bf16_t b[4]; uint64_t u; } p;
    p.b[0] = (bf16_t)v.x; p.b[1] = (bf16_t)v.y;
    p.b[2] = (bf16_t)v.z; p.b[3] = (bf16_t)v.w;
    ((uint64_t*)out)[i] = p.u;
  }
}

// ---------------- transpose + convert: in fp32 [R][C] -> out bf16 [C][R] ----
__global__ __launch_bounds__(256) void k_tcvt(const float* __restrict__ in,
                                              bf16_t* __restrict__ out, int R, int C) {
  __shared__ float tile[32][33];
  int c0 = blockIdx.x * 32, r0 = blockIdx.y * 32;
  int tx = threadIdx.x & 31, ty = threadIdx.x >> 5;
#pragma unroll
  for (int i = 0; i < 4; i++) {
    int r = ty + i * 8;
    tile[r][tx] = in[(size_t)(r0 + r) * C + c0 + tx];
  }
  __syncthreads();
#pragma unroll
  for (int i = 0; i < 4; i++) {
    int c = ty + i * 8;
    out[(size_t)(c0 + c) * R + r0 + tx] = (bf16_t)tile[tx][c];
  }
}

// ---------------- QKV GEMM + bias + RoPE + scatter ----------------
__global__ __launch_bounds__(256) void k_qkv(
    const bf16_t* __restrict__ A,   // [4096][1024]
    const bf16_t* __restrict__ Bt,  // [3072][1024]
    const float* __restrict__ bias, // [3072]
    const float* __restrict__ cs,   // [4096][32]
    const float* __restrict__ sn,   // [4096][32]
    bf16_t* __restrict__ qb, bf16_t* __restrict__ kb, bf16_t* __restrict__ vT) {
  constexpr int K = 1024, BK = 32;
  __shared__ bf16_t As[128 * BK] __attribute__((aligned(16)));
  __shared__ bf16_t Bs[128 * BK] __attribute__((aligned(16)));
  const int t = threadIdx.x;
  const int lane = t & 63, w = t >> 6;
  const int lrow = lane & 15, quad = lane >> 4;
  const int m0 = blockIdx.y * 128, n0 = blockIdx.x * 128;
  const int wm = (w >> 1) * 64, wn = (w & 1) * 64;

  const floatx4 ZV = {0.f, 0.f, 0.f, 0.f};
  floatx4 acc[4][4];
#pragma unroll
  for (int i = 0; i < 4; i++)
#pragma unroll
    for (int j = 0; j < 4; j++) acc[i][j] = ZV;

  for (int kt = 0; kt < K; kt += BK) {
#pragma unroll
    for (int r = 0; r < 2; r++) {
      int idx = r * 256 + t;
      int lbase = (r * 256 + w * 64) * 8;
      async_ld16(&A[(size_t)(m0 + (idx >> 2)) * K + kt + (idx & 3) * 8], &As[lbase]);
      async_ld16(&Bt[(size_t)(n0 + (idx >> 2)) * K + kt + (idx & 3) * 8], &Bs[lbase]);
    }
    __syncthreads();
    bf16x8 af[4], bf[4];
#pragma unroll
    for (int i = 0; i < 4; i++)
      af[i] = *(const bf16x8*)&As[(wm + i * 16 + lrow) * BK + quad * 8];
#pragma unroll
    for (int i = 0; i < 4; i++)
      bf[i] = *(const bf16x8*)&Bs[(wn + i * 16 + lrow) * BK + quad * 8];
#pragma unroll
    for (int mi = 0; mi < 4; mi++)
#pragma unroll
      for (int ni = 0; ni < 4; ni++)
        acc[mi][ni] = __builtin_amdgcn_mfma_f32_16x16x32_bf16(af[mi], bf[ni], acc[mi][ni], 0, 0, 0);
    __syncthreads();
  }

  // Epilogue: wave covers cols [c0, c0+64) = exactly one head of one of q/k/v.
  const int c0 = n0 + wn;
  const int seg = c0 >> 10;           // 0=q 1=k 2=v
  const int h = (c0 & 1023) >> 6;
  float bv[4];
#pragma unroll
  for (int ni = 0; ni < 4; ni++) bv[ni] = bias[c0 + ni * 16 + lrow];

  if (seg < 2) {
    bf16_t* base = ((seg == 0) ? qb : kb) + (size_t)h * TOK * HDIM;
    const float qs = (seg == 0) ? SCALE_LOG2E : 1.0f;
#pragma unroll
    for (int mi = 0; mi < 4; mi++) {
#pragma unroll
      for (int reg = 0; reg < 4; reg++) {
        const int r = m0 + wm + mi * 16 + quad * 4 + reg;
        const float c_lo = cs[r * 32 + lrow];
        const float c_hi = cs[r * 32 + 16 + lrow];
        const float s_lo = sn[r * 32 + lrow];
        const float s_hi = sn[r * 32 + 16 + lrow];
        const float v0 = acc[mi][0][reg] + bv[0];
        const float v1 = acc[mi][1][reg] + bv[1];
        const float v2 = acc[mi][2][reg] + bv[2];
        const float v3 = acc[mi][3][reg] + bv[3];
        // RoPE: d<32: v*cos - v[d+32]*sin ; d>=32: v*cos + v[d-32]*sin
        const float o0 = (v0 * c_lo - v2 * s_lo) * qs;
        const float o1 = (v1 * c_hi - v3 * s_hi) * qs;
        const float o2 = (v2 * c_lo + v0 * s_lo) * qs;
        const float o3 = (v3 * c_hi + v1 * s_hi) * qs;
        bf16_t* rp = base + (size_t)r * HDIM + lrow;
        rp[0]  = (bf16_t)o0;
        rp[16] = (bf16_t)o1;
        rp[32] = (bf16_t)o2;
        rp[48] = (bf16_t)o3;
      }
    }
  } else {
    // V: store transposed [h][d][n]; 4 acc regs = 4 consecutive rows -> 8B store
    bf16_t* base = vT + (size_t)h * HDIM * TOK;
#pragma unroll
    for (int mi = 0; mi < 4; mi++) {
      const int rbase = m0 + wm + mi * 16 + quad * 4;
#pragma unroll
      for (int ni = 0; ni < 4; ni++) {
        union { bf16_t b[4]; uint64_t u; } p;
#pragma unroll
        for (int reg = 0; reg < 4; reg++) p.b[reg] = (bf16_t)(acc[mi][ni][reg] + bv[ni]);
        *(uint64_t*)&base[(size_t)(ni * 16 + lrow) * TOK + rbase] = p.u;
      }
    }
  }
}

// ---------------- flash attention (non-causal) ----------------
__global__ __launch_bounds__(256) void k_attn(
    const bf16_t* __restrict__ qb, const bf16_t* __restrict__ kb,
    const bf16_t* __restrict__ vT, bf16_t* __restrict__ ao) {
  __shared__ bf16_t Ks[64 * 64] __attribute__((aligned(16)));
  __shared__ bf16_t Vs[64 * 64] __attribute__((aligned(16)));
  __shared__ bf16_t Ps[4][32 * 64] __attribute__((aligned(16)));
  const int t = threadIdx.x, lane = t & 63, w = t >> 6;
  const int lrow = lane & 15, quad = lane >> 4;
  const int h = blockIdx.y;
  const int q0 = blockIdx.x * 128;
  const bf16_t* qh = qb + (size_t)h * TOK * HDIM;
  const bf16_t* kh = kb + (size_t)h * TOK * HDIM;
  const bf16_t* vh = vT + (size_t)h * HDIM * TOK;

  // Q fragments straight from global (A-layout: row = lane&15, k contiguous)
  bf16x8 qf[2][2];
#pragma unroll
  for (int mi = 0; mi < 2; mi++)
#pragma unroll
    for (int ks = 0; ks < 2; ks++)
      qf[mi][ks] = *(const bf16x8*)&qh[(size_t)(q0 + w * 32 + mi * 16 + lrow) * HDIM + ks * 32 + quad * 8];

  const floatx4 ZV = {0.f, 0.f, 0.f, 0.f};
  floatx4 o[2][4];
  float mst[2][4], lst[2][4];
#pragma unroll
  for (int mi = 0; mi < 2; mi++)
#pragma unroll
    for (int i = 0; i < 4; i++) { mst[mi][i] = -1e30f; lst[mi][i] = 0.f; o[mi][i] = ZV; }

  for (int j0 = 0; j0 < TOK; j0 += 64) {
#pragma unroll
    for (int r = 0; r < 2; r++) {
      int idx = r * 256 + t;
      int lbase = (r * 256 + w * 64) * 8;
      async_ld16(&kh[(size_t)(j0 + (idx >> 3)) * HDIM + (idx & 7) * 8], &Ks[lbase]);
      async_ld16(&vh[(size_t)(idx >> 3) * TOK + j0 + (idx & 7) * 8], &Vs[lbase]);
    }
    __syncthreads();

    // S = Q K^T (q pre-scaled by SCALE*log2e)
    floatx4 s[2][4];
#pragma unroll
    for (int mi = 0; mi < 2; mi++)
#pragma unroll
      for (int ni = 0; ni < 4; ni++) s[mi][ni] = ZV;
#pragma unroll
    for (int ks = 0; ks < 2; ks++) {
      bf16x8 kf[4];
#pragma unroll
      for (int ni = 0; ni < 4; ni++)
        kf[ni] = *(const bf16x8*)&Ks[(ni * 16 + lrow) * 64 + ks * 32 + quad * 8];
#pragma unroll
      for (int mi = 0; mi < 2; mi++)
#pragma unroll
        for (int ni = 0; ni < 4; ni++)
          s[mi][ni] = __builtin_amdgcn_mfma_f32_16x16x32_bf16(qf[mi][ks], kf[ni], s[mi][ni], 0, 0, 0);
    }

    // online softmax (base-2). Row = mi*16 + quad*4 + reg; 16 lanes (lrow) share it.
    float alpha[2][4];
#pragma unroll
    for (int mi = 0; mi < 2; mi++)
#pragma unroll
      for (int reg = 0; reg < 4; reg++) {
        float rm = fmaxf(fmaxf(s[mi][0][reg], s[mi][1][reg]),
                         fmaxf(s[mi][2][reg], s[mi][3][reg]));
#pragma unroll
        for (int off = 1; off < 16; off <<= 1) rm = fmaxf(rm, __shfl_xor(rm, off, 64));
        float mn = fmaxf(mst[mi][reg], rm);
        float al = __builtin_amdgcn_exp2f(mst[mi][reg] - mn);
        mst[mi][reg] = mn;
        float rs = 0.f;
#pragma unroll
        for (int ni = 0; ni < 4; ni++) {
          float p = __builtin_amdgcn_exp2f(s[mi][ni][reg] - mn);
          s[mi][ni][reg] = p;
          rs += p;
        }
#pragma unroll
        for (int off = 1; off < 16; off <<= 1) rs += __shfl_xor(rs, off, 64);
        lst[mi][reg] = lst[mi][reg] * al + rs;
        alpha[mi][reg] = al;
      }

    // P -> per-wave LDS (C-layout -> A-layout), rescale O
#pragma unroll
    for (int mi = 0; mi < 2; mi++) {
#pragma unroll
      for (int ni = 0; ni < 4; ni++)
#pragma unroll
        for (int reg = 0; reg < 4; reg++)
          Ps[w][(mi * 16 + quad * 4 + reg) * 64 + ni * 16 + lrow] = (bf16_t)s[mi][ni][reg];
#pragma unroll
      for (int di = 0; di < 4; di++)
#pragma unroll
        for (int reg = 0; reg < 4; reg++) o[mi][di][reg] *= alpha[mi][reg];
    }

    // O += P V  (B-fragments from v^T tile)
#pragma unroll
    for (int ks = 0; ks < 2; ks++) {
      bf16x8 pf[2], vf[4];
#pragma unroll
      for (int mi = 0; mi < 2; mi++)
        pf[mi] = *(const bf16x8*)&Ps[w][(mi * 16 + lrow) * 64 + ks * 32 + quad * 8];
#pragma unroll
      for (int di = 0; di < 4; di++)
        vf[di] = *(const bf16x8*)&Vs[(di * 16 + lrow) * 64 + ks * 32 + quad * 8];
#pragma unroll
      for (int mi = 0; mi < 2; mi++)
#pragma unroll
        for (int di = 0; di < 4; di++)
          o[mi][di] = __builtin_amdgcn_mfma_f32_16x16x32_bf16(pf[mi], vf[di], o[mi][di], 0, 0, 0);
    }
    __syncthreads();
  }

#pragma unroll
  for (int mi = 0; mi < 2; mi++)
#pragma unroll
    for (int reg = 0; reg < 4; reg++) {
      float inv = 1.0f / lst[mi][reg];
      int r = q0 + w * 32 + mi * 16 + quad * 4 + reg;
#pragma unroll
      for (int di = 0; di < 4; di++)
        ao[(size_t)r * DIM_ + h * HDIM + di * 16 + lrow] = (bf16_t)(o[mi][di][reg] * inv);
    }
}

// ---------------- proj GEMM + bias (fp32 out) ----------------
__global__ __launch_bounds__(256) void k_proj(
    const bf16_t* __restrict__ A,   // [4096][1024]
    const bf16_t* __restrict__ Bt,  // [1024][1024]
    const float* __restrict__ bias, float* __restrict__ out) {
  constexpr int K = 1024, BK = 32;
  __shared__ bf16_t As[128 * BK] __attribute__((aligned(16)));
  __shared__ bf16_t Bs[128 * BK] __attribute__((aligned(16)));
  const int t = threadIdx.x;
  const int lane = t & 63, w = t >> 6;
  const int lrow = lane & 15, quad = lane >> 4;
  const int m0 = blockIdx.y * 128, n0 = blockIdx.x * 128;
  const int wm = (w >> 1) * 64, wn = (w & 1) * 64;

  const floatx4 ZV = {0.f, 0.f, 0.f, 0.f};
  floatx4 acc[4][4];
#pragma unroll
  for (int i = 0; i < 4; i++)
#pragma unroll
    for (int j = 0; j < 4; j++) acc[i][j] = ZV;

  for (int kt = 0; kt < K; kt += BK) {
#pragma unroll
    for (int r = 0; r < 2; r++) {
      int idx = r * 256 + t;
      int lbase = (r * 256 + w * 64) * 8;
      async_ld16(&A[(size_t)(m0 + (idx >> 2)) * K + kt + (idx & 3) * 8], &As[lbase]);
      async_ld16(&Bt[(size_t)(n0 + (idx >> 2)) * K + kt + (idx & 3) * 8], &Bs[lbase]);
    }
    __syncthreads();
    bf16x8 af[4], bf[4];
#pragma unroll
    for (int i = 0; i < 4; i++)
      af[i] = *(const bf16x8*)&As[(wm + i * 16 + lrow) * BK + quad * 8];
#pragma unroll
    for (int i = 0; i < 4; i++)
      bf[i] = *(const bf16x8*)&Bs[(wn + i * 16 + lrow) * BK + quad * 8];
#pragma unroll
    for (int mi = 0; mi < 4; mi++)
#pragma unroll
      for (int ni = 0; ni < 4; ni++)
        acc[mi][ni] = __builtin_amdgcn_mfma_f32_16x16x32_bf16(af[mi], bf[ni], acc[mi][ni], 0, 0, 0);
    __syncthreads();
  }

  const int c0 = n0 + wn;
#pragma unroll
  for (int ni = 0; ni < 4; ni++) {
    float bv = bias[c0 + ni * 16 + lrow];
#pragma unroll
    for (int mi = 0; mi < 4; mi++)
#pragma unroll
      for (int reg = 0; reg < 4; reg++) {
        int r = m0 + wm + mi * 16 + quad * 4 + reg;
        out[(size_t)r * DIM_ + c0 + ni * 16 + lrow] = acc[mi][ni][reg] + bv;
      }
  }
}

extern "C" void kernel_launch(void* const* d_in, const int* in_sizes, int n_in,
                              void* d_out, int out_size, void* d_ws, size_t ws_size,
                              hipStream_t stream) {
  const float* x      = (const float*)d_in[0];
  const float* cs     = (const float*)d_in[1];
  const float* sn     = (const float*)d_in[2];
  const float* w_qkv  = (const float*)d_in[3];
  const float* b_qkv  = (const float*)d_in[4];
  const float* w_proj = (const float*)d_in[5];
  const float* b_proj = (const float*)d_in[6];
  float* out = (float*)d_out;

  char* ws = (char*)d_ws;
  bf16_t* xb     = (bf16_t*)(ws);
  bf16_t* wqkvT  = (bf16_t*)(ws + 8388608);
  bf16_t* wprojT = (bf16_t*)(ws + 14680064);
  bf16_t* qb     = (bf16_t*)(ws + 16777216);
  bf16_t* kb     = (bf16_t*)(ws + 25165824);
  bf16_t* vT     = (bf16_t*)(ws + 33554432);
  bf16_t* ao     = xb;  // x is dead after k_qkv; reuse its region

  k_cvt<<<dim3(4096), dim3(256), 0, stream>>>(x, xb, 1048576);
  k_tcvt<<<dim3(96, 32), dim3(256), 0, stream>>>(w_qkv, wqkvT, 1024, 3072);
  k_tcvt<<<dim3(32, 32), dim3(256), 0, stream>>>(w_proj, wprojT, 1024, 1024);
  k_qkv<<<dim3(24, 32), dim3(256), 0, stream>>>(xb, wqkvT, b_qkv, cs, sn, qb, kb, vT);
  k_attn<<<dim3(32, 16), dim3(256), 0, stream>>>(qb, kb, vT, ao);
  k_proj<<<dim3(8, 32), dim3(256), 0, stream>>>(ao, wprojT, b_proj, out);
}

// Round 2
// 313.849 us; speedup vs baseline: 1.2515x; 1.2515x over previous
//
#include <hip/hip_runtime.h>
#include <hip/hip_bf16.h>
#include <cstdint>

// Workspace layout (bytes):
//   [0,        8388608)  xb   : x as bf16 [4096][1024]   (aliased later as ao)
//   [8388608, 14680064)  wqkvT: w_qkv^T bf16 [3072][1024]
//   [14680064,16777216)  wprojT: w_proj^T bf16 [1024][1024]
//   [16777216,25165824)  qb   : q (rope'd, *SCALE*log2e) bf16 [16][4096][64]
//   [25165824,33554432)  kb   : k (rope'd) bf16 [16][4096][64]
//   [33554432,41943040)  vT   : v^T bf16 [16][64][4096]
//   ao (attention out bf16 [4096][1024]) aliases xb.

#define TOK 4096
#define DIM_ 1024
#define NHEAD 16
#define HDIM 64
#define N3 3072
#define SCALE_LOG2E 0.18033688011112042f  // (1/8) * log2(e)

typedef __bf16 bf16_t;
typedef bf16_t bf16x8 __attribute__((ext_vector_type(8)));
typedef float floatx4 __attribute__((ext_vector_type(4)));

__device__ __forceinline__ void async_ld16(const bf16_t* g, bf16_t* l) {
  __builtin_amdgcn_global_load_lds(
      (const __attribute__((address_space(1))) void*)(g),
      (__attribute__((address_space(3))) void*)(l), 16, 0, 0);
}

// ---------------- convert x -> bf16 ----------------
__global__ __launch_bounds__(256) void k_cvt(const float* __restrict__ in,
                                             bf16_t* __restrict__ out, int n4) {
  int i = blockIdx.x * 256 + threadIdx.x;
  if (i < n4) {
    float4 v = ((const float4*)in)[i];
    union { bf16_t b[4]; uint64_t u; } p;
    p.b[0] = (bf16_t)v.x; p.b[1] = (bf16_t)v.y;
    p.b[2] = (bf16_t)v.z; p.b[3] = (bf16_t)v.w;
    ((uint64_t*)out)[i] = p.u;
  }
}

// ---------------- transpose + convert: in fp32 [R][C] -> out bf16 [C][R] ----
__global__ __launch_bounds__(256) void k_tcvt(const float* __restrict__ in,
                                              bf16_t* __restrict__ out, int R, int C) {
  __shared__ float tile[32][33];
  int c0 = blockIdx.x * 32, r0 = blockIdx.y * 32;
  int tx = threadIdx.x & 31, ty = threadIdx.x >> 5;
#pragma unroll
  for (int i = 0; i < 4; i++) {
    int r = ty + i * 8;
    tile[r][tx] = in[(size_t)(r0 + r) * C + c0 + tx];
  }
  __syncthreads();
#pragma unroll
  for (int i = 0; i < 4; i++) {
    int c = ty + i * 8;
    out[(size_t)(c0 + c) * R + r0 + tx] = (bf16_t)tile[tx][c];
  }
}

// ---------------- QKV GEMM + bias + RoPE + scatter ----------------
__global__ __launch_bounds__(256) void k_qkv(
    const bf16_t* __restrict__ A,   // [4096][1024]
    const bf16_t* __restrict__ Bt,  // [3072][1024]
    const float* __restrict__ bias, // [3072]
    const float* __restrict__ cs,   // [4096][32]
    const float* __restrict__ sn,   // [4096][32]
    bf16_t* __restrict__ qb, bf16_t* __restrict__ kb, bf16_t* __restrict__ vT) {
  constexpr int K = 1024, BK = 32;
  __shared__ bf16_t As[128 * BK] __attribute__((aligned(16)));
  __shared__ bf16_t Bs[128 * BK] __attribute__((aligned(16)));
  const int t = threadIdx.x;
  const int lane = t & 63, w = t >> 6;
  const int lrow = lane & 15, quad = lane >> 4;
  const int m0 = blockIdx.y * 128, n0 = blockIdx.x * 128;
  const int wm = (w >> 1) * 64, wn = (w & 1) * 64;

  const floatx4 ZV = {0.f, 0.f, 0.f, 0.f};
  floatx4 acc[4][4];
#pragma unroll
  for (int i = 0; i < 4; i++)
#pragma unroll
    for (int j = 0; j < 4; j++) acc[i][j] = ZV;

  for (int kt = 0; kt < K; kt += BK) {
#pragma unroll
    for (int r = 0; r < 2; r++) {
      int idx = r * 256 + t;
      int lbase = (r * 256 + w * 64) * 8;
      async_ld16(&A[(size_t)(m0 + (idx >> 2)) * K + kt + (idx & 3) * 8], &As[lbase]);
      async_ld16(&Bt[(size_t)(n0 + (idx >> 2)) * K + kt + (idx & 3) * 8], &Bs[lbase]);
    }
    __syncthreads();
    bf16x8 af[4], bf[4];
#pragma unroll
    for (int i = 0; i < 4; i++)
      af[i] = *(const bf16x8*)&As[(wm + i * 16 + lrow) * BK + quad * 8];
#pragma unroll
    for (int i = 0; i < 4; i++)
      bf[i] = *(const bf16x8*)&Bs[(wn + i * 16 + lrow) * BK + quad * 8];
#pragma unroll
    for (int mi = 0; mi < 4; mi++)
#pragma unroll
      for (int ni = 0; ni < 4; ni++)
        acc[mi][ni] = __builtin_amdgcn_mfma_f32_16x16x32_bf16(af[mi], bf[ni], acc[mi][ni], 0, 0, 0);
    __syncthreads();
  }

  // Epilogue: wave covers cols [c0, c0+64) = exactly one head of one of q/k/v.
  const int c0 = n0 + wn;
  const int seg = c0 >> 10;           // 0=q 1=k 2=v
  const int h = (c0 & 1023) >> 6;
  float bv[4];
#pragma unroll
  for (int ni = 0; ni < 4; ni++) bv[ni] = bias[c0 + ni * 16 + lrow];

  if (seg < 2) {
    bf16_t* base = ((seg == 0) ? qb : kb) + (size_t)h * TOK * HDIM;
    const float qs = (seg == 0) ? SCALE_LOG2E : 1.0f;
#pragma unroll
    for (int mi = 0; mi < 4; mi++) {
#pragma unroll
      for (int reg = 0; reg < 4; reg++) {
        const int r = m0 + wm + mi * 16 + quad * 4 + reg;
        const float c_lo = cs[r * 32 + lrow];
        const float c_hi = cs[r * 32 + 16 + lrow];
        const float s_lo = sn[r * 32 + lrow];
        const float s_hi = sn[r * 32 + 16 + lrow];
        const float v0 = acc[mi][0][reg] + bv[0];
        const float v1 = acc[mi][1][reg] + bv[1];
        const float v2 = acc[mi][2][reg] + bv[2];
        const float v3 = acc[mi][3][reg] + bv[3];
        // RoPE: d<32: v*cos - v[d+32]*sin ; d>=32: v*cos + v[d-32]*sin
        const float o0 = (v0 * c_lo - v2 * s_lo) * qs;
        const float o1 = (v1 * c_hi - v3 * s_hi) * qs;
        const float o2 = (v2 * c_lo + v0 * s_lo) * qs;
        const float o3 = (v3 * c_hi + v1 * s_hi) * qs;
        bf16_t* rp = base + (size_t)r * HDIM + lrow;
        rp[0]  = (bf16_t)o0;
        rp[16] = (bf16_t)o1;
        rp[32] = (bf16_t)o2;
        rp[48] = (bf16_t)o3;
      }
    }
  } else {
    // V: store transposed [h][d][n]; 4 acc regs = 4 consecutive rows -> 8B store
    bf16_t* base = vT + (size_t)h * HDIM * TOK;
#pragma unroll
    for (int mi = 0; mi < 4; mi++) {
      const int rbase = m0 + wm + mi * 16 + quad * 4;
#pragma unroll
      for (int ni = 0; ni < 4; ni++) {
        union { bf16_t b[4]; uint64_t u; } p;
#pragma unroll
        for (int reg = 0; reg < 4; reg++) p.b[reg] = (bf16_t)(acc[mi][ni][reg] + bv[ni]);
        *(uint64_t*)&base[(size_t)(ni * 16 + lrow) * TOK + rbase] = p.u;
      }
    }
  }
}

// ---------------- flash attention v2 (S^T formulation) ----------------
// Wave = 32 q rows (ni=2 n-tiles), block = 4 waves = 128 q rows.
// KV tile = 128 keys. S^T = K*Q^T so softmax is per-lane (col = q).
// Ks: [128 key][64 d], 16B chunks XOR-swizzled by key&7  (bank-even reads)
// Vs: [64 d][128 key], 16B chunks XOR-swizzled by d&15   (bank-even reads)
// Ps: per-wave [32 q][72], b64 writes / b128 reads, 2-way max (free)
__global__ __launch_bounds__(256) void k_attn(
    const bf16_t* __restrict__ qb, const bf16_t* __restrict__ kb,
    const bf16_t* __restrict__ vT, bf16_t* __restrict__ ao) {
  __shared__ bf16_t Ks[128 * 64] __attribute__((aligned(16)));
  __shared__ bf16_t Vs[64 * 128] __attribute__((aligned(16)));
  __shared__ bf16_t Ps[4][32 * 72] __attribute__((aligned(16)));
  const int t = threadIdx.x, lane = t & 63, w = t >> 6;
  const int lrow = lane & 15, quad = lane >> 4;
  const int h = blockIdx.y;
  const int q0 = blockIdx.x * 128;
  const bf16_t* qh = qb + (size_t)h * TOK * HDIM;
  const bf16_t* kh = kb + (size_t)h * TOK * HDIM;
  const bf16_t* vh = vT + (size_t)h * HDIM * TOK;
  bf16_t* Pw = &Ps[w][0];

  // Lane-constant staging source offsets (XOR swizzle folded in; see layout note)
  const int ksrc = ((t >> 3) * HDIM) + (((t & 7) ^ ((t >> 3) & 7)) * 8);
  const int vsrc = ((t >> 4) * TOK) + (((t & 15) ^ (t >> 4)) * 8);
  const int lds_w = w * 512;  // per-wave chunk base (64 chunks * 8 elems)

  // Q B-fragments (B[n=q][k=d], k contiguous) straight from global, once.
  bf16x8 qf[2][2];
#pragma unroll
  for (int ni = 0; ni < 2; ni++)
#pragma unroll
    for (int ks = 0; ks < 2; ks++)
      qf[ni][ks] = *(const bf16x8*)&qh[(size_t)(q0 + w * 32 + ni * 16 + lrow) * HDIM + ks * 32 + quad * 8];

  const floatx4 ZV = {0.f, 0.f, 0.f, 0.f};
  floatx4 o[4][2];           // O^T [d-tile][ni]
  float mst[2], lst[2];
#pragma unroll
  for (int ni = 0; ni < 2; ni++) {
    mst[ni] = -1e30f; lst[ni] = 0.f;
#pragma unroll
    for (int d = 0; d < 4; d++) o[d][ni] = ZV;
  }

  for (int j0 = 0; j0 < TOK; j0 += 128) {
#pragma unroll
    for (int r = 0; r < 4; r++) {
      async_ld16(&kh[(size_t)j0 * HDIM + r * 2048 + ksrc], &Ks[r * 2048 + lds_w]);
      async_ld16(&vh[(size_t)r * 16 * TOK + j0 + vsrc], &Vs[r * 2048 + lds_w]);
    }
    __syncthreads();

    // ---- S^T = K * Q^T : D[m=key][n=q]; col=q=lane&15, row=key=quad*4+reg
    floatx4 s[8][2];
#pragma unroll
    for (int mi = 0; mi < 8; mi++)
#pragma unroll
      for (int ni = 0; ni < 2; ni++) s[mi][ni] = ZV;
#pragma unroll
    for (int ks = 0; ks < 2; ks++)
#pragma unroll
      for (int mi = 0; mi < 8; mi++) {
        bf16x8 kf = *(const bf16x8*)&Ks[(mi * 16 + lrow) * 64 + (((ks * 4 + quad) ^ (lrow & 7)) * 8)];
#pragma unroll
        for (int ni = 0; ni < 2; ni++)
          s[mi][ni] = __builtin_amdgcn_mfma_f32_16x16x32_bf16(kf, qf[ni][ks], s[mi][ni], 0, 0, 0);
      }

    // ---- online softmax: per-lane over 32 in-lane values + butterfly over quads
    float alpha[2];
#pragma unroll
    for (int ni = 0; ni < 2; ni++) {
      float mx = s[0][ni][0];
#pragma unroll
      for (int mi = 0; mi < 8; mi++)
#pragma unroll
        for (int reg = 0; reg < 4; reg++) mx = fmaxf(mx, s[mi][ni][reg]);
      mx = fmaxf(mx, __shfl_xor(mx, 16, 64));
      mx = fmaxf(mx, __shfl_xor(mx, 32, 64));
      const float mn = fmaxf(mst[ni], mx);
      alpha[ni] = __builtin_amdgcn_exp2f(mst[ni] - mn);
      mst[ni] = mn;
      float rs = 0.f;
#pragma unroll
      for (int mi = 0; mi < 8; mi++)
#pragma unroll
        for (int reg = 0; reg < 4; reg++) {
          float p = __builtin_amdgcn_exp2f(s[mi][ni][reg] - mn);
          s[mi][ni][reg] = p;
          rs += p;
        }
      rs += __shfl_xor(rs, 16, 64);
      rs += __shfl_xor(rs, 32, 64);
      lst[ni] = lst[ni] * alpha[ni] + rs;
#pragma unroll
      for (int d = 0; d < 4; d++) o[d][ni] *= alpha[ni];
    }

    // ---- PV in two 64-key halves through per-wave Ps (C-layout -> B-layout)
#pragma unroll
    for (int half = 0; half < 2; half++) {
#pragma unroll
      for (int miL = 0; miL < 4; miL++)
#pragma unroll
        for (int ni = 0; ni < 2; ni++) {
          union { bf16_t b[4]; uint32_t u[2]; } p;
#pragma unroll
          for (int reg = 0; reg < 4; reg++) p.b[reg] = (bf16_t)s[half * 4 + miL][ni][reg];
          *(uint32_t*)&Pw[(ni * 16 + lrow) * 72 + miL * 16 + quad * 4] = p.u[0];
          *(uint32_t*)&Pw[(ni * 16 + lrow) * 72 + miL * 16 + quad * 4 + 2] = p.u[1];
        }
#pragma unroll
      for (int ks = 0; ks < 2; ks++) {
        bf16x8 pf[2];
#pragma unroll
        for (int ni = 0; ni < 2; ni++)
          pf[ni] = *(const bf16x8*)&Pw[(ni * 16 + lrow) * 72 + ks * 32 + quad * 8];
#pragma unroll
        for (int d = 0; d < 4; d++) {
          bf16x8 vf = *(const bf16x8*)&Vs[(d * 16 + lrow) * 128 + (((half * 8 + ks * 4 + quad) ^ lrow) * 8)];
#pragma unroll
          for (int ni = 0; ni < 2; ni++)
            o[d][ni] = __builtin_amdgcn_mfma_f32_16x16x32_bf16(vf, pf[ni], o[d][ni], 0, 0, 0);
        }
      }
    }
    __syncthreads();
  }

  // ---- epilogue: O^T regs are 4 consecutive d -> packed b64 stores
#pragma unroll
  for (int ni = 0; ni < 2; ni++) {
    const float inv = 1.0f / lst[ni];
    const int qrow = q0 + w * 32 + ni * 16 + lrow;
#pragma unroll
    for (int d = 0; d < 4; d++) {
      union { bf16_t b[4]; uint64_t u; } p;
#pragma unroll
      for (int reg = 0; reg < 4; reg++) p.b[reg] = (bf16_t)(o[d][ni][reg] * inv);
      *(uint64_t*)&ao[(size_t)qrow * DIM_ + h * HDIM + d * 16 + quad * 4] = p.u;
    }
  }
}

// ---------------- proj GEMM + bias (fp32 out) ----------------
__global__ __launch_bounds__(256) void k_proj(
    const bf16_t* __restrict__ A,   // [4096][1024]
    const bf16_t* __restrict__ Bt,  // [1024][1024]
    const float* __restrict__ bias, float* __restrict__ out) {
  constexpr int K = 1024, BK = 32;
  __shared__ bf16_t As[128 * BK] __attribute__((aligned(16)));
  __shared__ bf16_t Bs[128 * BK] __attribute__((aligned(16)));
  const int t = threadIdx.x;
  const int lane = t & 63, w = t >> 6;
  const int lrow = lane & 15, quad = lane >> 4;
  const int m0 = blockIdx.y * 128, n0 = blockIdx.x * 128;
  const int wm = (w >> 1) * 64, wn = (w & 1) * 64;

  const floatx4 ZV = {0.f, 0.f, 0.f, 0.f};
  floatx4 acc[4][4];
#pragma unroll
  for (int i = 0; i < 4; i++)
#pragma unroll
    for (int j = 0; j < 4; j++) acc[i][j] = ZV;

  for (int kt = 0; kt < K; kt += BK) {
#pragma unroll
    for (int r = 0; r < 2; r++) {
      int idx = r * 256 + t;
      int lbase = (r * 256 + w * 64) * 8;
      async_ld16(&A[(size_t)(m0 + (idx >> 2)) * K + kt + (idx & 3) * 8], &As[lbase]);
      async_ld16(&Bt[(size_t)(n0 + (idx >> 2)) * K + kt + (idx & 3) * 8], &Bs[lbase]);
    }
    __syncthreads();
    bf16x8 af[4], bf[4];
#pragma unroll
    for (int i = 0; i < 4; i++)
      af[i] = *(const bf16x8*)&As[(wm + i * 16 + lrow) * BK + quad * 8];
#pragma unroll
    for (int i = 0; i < 4; i++)
      bf[i] = *(const bf16x8*)&Bs[(wn + i * 16 + lrow) * BK + quad * 8];
#pragma unroll
    for (int mi = 0; mi < 4; mi++)
#pragma unroll
      for (int ni = 0; ni < 4; ni++)
        acc[mi][ni] = __builtin_amdgcn_mfma_f32_16x16x32_bf16(af[mi], bf[ni], acc[mi][ni], 0, 0, 0);
    __syncthreads();
  }

  const int c0 = n0 + wn;
#pragma unroll
  for (int ni = 0; ni < 4; ni++) {
    float bv = bias[c0 + ni * 16 + lrow];
#pragma unroll
    for (int mi = 0; mi < 4; mi++)
#pragma unroll
      for (int reg = 0; reg < 4; reg++) {
        int r = m0 + wm + mi * 16 + quad * 4 + reg;
        out[(size_t)r * DIM_ + c0 + ni * 16 + lrow] = acc[mi][ni][reg] + bv;
      }
  }
}

extern "C" void kernel_launch(void* const* d_in, const int* in_sizes, int n_in,
                              void* d_out, int out_size, void* d_ws, size_t ws_size,
                              hipStream_t stream) {
  const float* x      = (const float*)d_in[0];
  const float* cs     = (const float*)d_in[1];
  const float* sn     = (const float*)d_in[2];
  const float* w_qkv  = (const float*)d_in[3];
  const float* b_qkv  = (const float*)d_in[4];
  const float* w_proj = (const float*)d_in[5];
  const float* b_proj = (const float*)d_in[6];
  float* out = (float*)d_out;

  char* ws = (char*)d_ws;
  bf16_t* xb     = (bf16_t*)(ws);
  bf16_t* wqkvT  = (bf16_t*)(ws + 8388608);
  bf16_t* wprojT = (bf16_t*)(ws + 14680064);
  bf16_t* qb     = (bf16_t*)(ws + 16777216);
  bf16_t* kb     = (bf16_t*)(ws + 25165824);
  bf16_t* vT     = (bf16_t*)(ws + 33554432);
  bf16_t* ao     = xb;  // x is dead after k_qkv; reuse its region

  k_cvt<<<dim3(4096), dim3(256), 0, stream>>>(x, xb, 1048576);
  k_tcvt<<<dim3(96, 32), dim3(256), 0, stream>>>(w_qkv, wqkvT, 1024, 3072);
  k_tcvt<<<dim3(32, 32), dim3(256), 0, stream>>>(w_proj, wprojT, 1024, 1024);
  k_qkv<<<dim3(24, 32), dim3(256), 0, stream>>>(xb, wqkvT, b_qkv, cs, sn, qb, kb, vT);
  k_attn<<<dim3(32, 16), dim3(256), 0, stream>>>(qb, kb, vT, ao);
  k_proj<<<dim3(8, 32), dim3(256), 0, stream>>>(ao, wprojT, b_proj, out);
}

// Round 3
// 287.027 us; speedup vs baseline: 1.3685x; 1.0934x over previous
//
#include <hip/hip_runtime.h>
#include <hip/hip_bf16.h>
#include <cstdint>

// Workspace layout (bytes):
//   [0,        8388608)  xb   : x as bf16 [4096][1024]   (aliased later as ao)
//   [8388608, 14680064)  wqkvT: w_qkv^T bf16 [3072][1024]
//   [14680064,16777216)  wprojT: w_proj^T bf16 [1024][1024]
//   [16777216,25165824)  qb   : q (rope'd, *SCALE*log2e) bf16 [16][4096][64]
//   [25165824,33554432)  kb   : k (rope'd) bf16 [16][4096][64]
//   [33554432,41943040)  vT   : v^T bf16 [16][64][4096]
//   ao (attention out bf16 [4096][1024]) aliases xb.

#define TOK 4096
#define DIM_ 1024
#define NHEAD 16
#define HDIM 64
#define N3 3072
#define SCALE_LOG2E 0.18033688011112042f  // (1/8) * log2(e)

typedef __bf16 bf16_t;
typedef bf16_t bf16x8 __attribute__((ext_vector_type(8)));
typedef float floatx4 __attribute__((ext_vector_type(4)));

__device__ __forceinline__ void async_ld16(const bf16_t* g, bf16_t* l) {
  __builtin_amdgcn_global_load_lds(
      (const __attribute__((address_space(1))) void*)(g),
      (__attribute__((address_space(3))) void*)(l), 16, 0, 0);
}

// ---------------- convert x -> bf16 ----------------
__global__ __launch_bounds__(256) void k_cvt(const float* __restrict__ in,
                                             bf16_t* __restrict__ out, int n4) {
  int i = blockIdx.x * 256 + threadIdx.x;
  if (i < n4) {
    float4 v = ((const float4*)in)[i];
    union { bf16_t b[4]; uint64_t u; } p;
    p.b[0] = (bf16_t)v.x; p.b[1] = (bf16_t)v.y;
    p.b[2] = (bf16_t)v.z; p.b[3] = (bf16_t)v.w;
    ((uint64_t*)out)[i] = p.u;
  }
}

// ---------------- transpose + convert: in fp32 [R][C] -> out bf16 [C][R] ----
__global__ __launch_bounds__(256) void k_tcvt(const float* __restrict__ in,
                                              bf16_t* __restrict__ out, int R, int C) {
  __shared__ float tile[32][33];
  int c0 = blockIdx.x * 32, r0 = blockIdx.y * 32;
  int tx = threadIdx.x & 31, ty = threadIdx.x >> 5;
#pragma unroll
  for (int i = 0; i < 4; i++) {
    int r = ty + i * 8;
    tile[r][tx] = in[(size_t)(r0 + r) * C + c0 + tx];
  }
  __syncthreads();
#pragma unroll
  for (int i = 0; i < 4; i++) {
    int c = ty + i * 8;
    out[(size_t)(c0 + c) * R + r0 + tx] = (bf16_t)tile[tx][c];
  }
}

// ---------------- QKV GEMM + bias + RoPE + scatter ----------------
__global__ __launch_bounds__(256) void k_qkv(
    const bf16_t* __restrict__ A,   // [4096][1024]
    const bf16_t* __restrict__ Bt,  // [3072][1024]
    const float* __restrict__ bias, // [3072]
    const float* __restrict__ cs,   // [4096][32]
    const float* __restrict__ sn,   // [4096][32]
    bf16_t* __restrict__ qb, bf16_t* __restrict__ kb, bf16_t* __restrict__ vT) {
  constexpr int K = 1024, BK = 32;
  __shared__ bf16_t As[128 * BK] __attribute__((aligned(16)));
  __shared__ bf16_t Bs[128 * BK] __attribute__((aligned(16)));
  const int t = threadIdx.x;
  const int lane = t & 63, w = t >> 6;
  const int lrow = lane & 15, quad = lane >> 4;
  const int m0 = blockIdx.y * 128, n0 = blockIdx.x * 128;
  const int wm = (w >> 1) * 64, wn = (w & 1) * 64;

  const floatx4 ZV = {0.f, 0.f, 0.f, 0.f};
  floatx4 acc[4][4];
#pragma unroll
  for (int i = 0; i < 4; i++)
#pragma unroll
    for (int j = 0; j < 4; j++) acc[i][j] = ZV;

  for (int kt = 0; kt < K; kt += BK) {
#pragma unroll
    for (int r = 0; r < 2; r++) {
      int idx = r * 256 + t;
      int lbase = (r * 256 + w * 64) * 8;
      async_ld16(&A[(size_t)(m0 + (idx >> 2)) * K + kt + (idx & 3) * 8], &As[lbase]);
      async_ld16(&Bt[(size_t)(n0 + (idx >> 2)) * K + kt + (idx & 3) * 8], &Bs[lbase]);
    }
    __syncthreads();
    bf16x8 af[4], bf[4];
#pragma unroll
    for (int i = 0; i < 4; i++)
      af[i] = *(const bf16x8*)&As[(wm + i * 16 + lrow) * BK + quad * 8];
#pragma unroll
    for (int i = 0; i < 4; i++)
      bf[i] = *(const bf16x8*)&Bs[(wn + i * 16 + lrow) * BK + quad * 8];
#pragma unroll
    for (int mi = 0; mi < 4; mi++)
#pragma unroll
      for (int ni = 0; ni < 4; ni++)
        acc[mi][ni] = __builtin_amdgcn_mfma_f32_16x16x32_bf16(af[mi], bf[ni], acc[mi][ni], 0, 0, 0);
    __syncthreads();
  }

  // Epilogue: wave covers cols [c0, c0+64) = exactly one head of one of q/k/v.
  const int c0 = n0 + wn;
  const int seg = c0 >> 10;           // 0=q 1=k 2=v
  const int h = (c0 & 1023) >> 6;
  float bv[4];
#pragma unroll
  for (int ni = 0; ni < 4; ni++) bv[ni] = bias[c0 + ni * 16 + lrow];

  if (seg < 2) {
    bf16_t* base = ((seg == 0) ? qb : kb) + (size_t)h * TOK * HDIM;
    const float qs = (seg == 0) ? SCALE_LOG2E : 1.0f;
#pragma unroll
    for (int mi = 0; mi < 4; mi++) {
#pragma unroll
      for (int reg = 0; reg < 4; reg++) {
        const int r = m0 + wm + mi * 16 + quad * 4 + reg;
        const float c_lo = cs[r * 32 + lrow];
        const float c_hi = cs[r * 32 + 16 + lrow];
        const float s_lo = sn[r * 32 + lrow];
        const float s_hi = sn[r * 32 + 16 + lrow];
        const float v0 = acc[mi][0][reg] + bv[0];
        const float v1 = acc[mi][1][reg] + bv[1];
        const float v2 = acc[mi][2][reg] + bv[2];
        const float v3 = acc[mi][3][reg] + bv[3];
        // RoPE: d<32: v*cos - v[d+32]*sin ; d>=32: v*cos + v[d-32]*sin
        const float o0 = (v0 * c_lo - v2 * s_lo) * qs;
        const float o1 = (v1 * c_hi - v3 * s_hi) * qs;
        const float o2 = (v2 * c_lo + v0 * s_lo) * qs;
        const float o3 = (v3 * c_hi + v1 * s_hi) * qs;
        bf16_t* rp = base + (size_t)r * HDIM + lrow;
        rp[0]  = (bf16_t)o0;
        rp[16] = (bf16_t)o1;
        rp[32] = (bf16_t)o2;
        rp[48] = (bf16_t)o3;
      }
    }
  } else {
    // V: store transposed [h][d][n]; 4 acc regs = 4 consecutive rows -> 8B store
    bf16_t* base = vT + (size_t)h * HDIM * TOK;
#pragma unroll
    for (int mi = 0; mi < 4; mi++) {
      const int rbase = m0 + wm + mi * 16 + quad * 4;
#pragma unroll
      for (int ni = 0; ni < 4; ni++) {
        union { bf16_t b[4]; uint64_t u; } p;
#pragma unroll
        for (int reg = 0; reg < 4; reg++) p.b[reg] = (bf16_t)(acc[mi][ni][reg] + bv[ni]);
        *(uint64_t*)&base[(size_t)(ni * 16 + lrow) * TOK + rbase] = p.u;
      }
    }
  }
}

// ---------------- flash attention v3 ----------------
// 2-wave blocks (64 q rows: 32 q/wave via ni=2), 64-key tiles.
// LDS = Ks 8K + Vs 8K + Ps 9.2K = 25.6 KB -> 4 co-resident blocks/CU (grid/CU)
// = 4 independent barrier groups of 2 waves each.
// Grid flattened so h = blockIdx.x & 15 -> same-head blocks share an XCD
// (2 heads/XCD = 2 MB K/V working set < 4 MB L2).
// l-sum kept as per-lane partials (alpha quad-uniform); butterflied in epilogue.
__global__ __launch_bounds__(128) void k_attn(
    const bf16_t* __restrict__ qb, const bf16_t* __restrict__ kb,
    const bf16_t* __restrict__ vT, bf16_t* __restrict__ ao) {
  __shared__ bf16_t Ks[64 * 64] __attribute__((aligned(16)));
  __shared__ bf16_t Vs[64 * 64] __attribute__((aligned(16)));
  __shared__ bf16_t Ps[2][32 * 72] __attribute__((aligned(16)));
  const int t = threadIdx.x, lane = t & 63, w = t >> 6;
  const int lrow = lane & 15, quad = lane >> 4;
  const int h = blockIdx.x & 15;
  const int q0 = (blockIdx.x >> 4) * 64;
  const bf16_t* qh = qb + (size_t)h * TOK * HDIM;
  const bf16_t* kh = kb + (size_t)h * TOK * HDIM;
  const bf16_t* vh = vT + (size_t)h * HDIM * TOK;
  bf16_t* Pw = &Ps[w][0];

  // Staging source offsets (XOR swizzle folded in; lane-constant per instr).
  // Round r covers rows r*16+(t>>3); 8 chunks/row, phys chunk = c ^ (row&7).
  const int ksrc = (t >> 3) * HDIM + (((t & 7) ^ ((t >> 3) & 7)) * 8);
  const int vsrc = (t >> 3) * TOK + (((t & 7) ^ ((t >> 3) & 7)) * 8);

  // Q B-fragments (B[n=q][k=d], k contiguous) straight from global, once.
  bf16x8 qf[2][2];
#pragma unroll
  for (int ni = 0; ni < 2; ni++)
#pragma unroll
    for (int ks = 0; ks < 2; ks++)
      qf[ni][ks] = *(const bf16x8*)&qh[(size_t)(q0 + w * 32 + ni * 16 + lrow) * HDIM + ks * 32 + quad * 8];

  const floatx4 ZV = {0.f, 0.f, 0.f, 0.f};
  floatx4 o[4][2];           // O^T [d-tile][ni]
  float mst[2], lst[2];
#pragma unroll
  for (int ni = 0; ni < 2; ni++) {
    mst[ni] = -1e30f; lst[ni] = 0.f;
#pragma unroll
    for (int d = 0; d < 4; d++) o[d][ni] = ZV;
  }

  for (int j0 = 0; j0 < TOK; j0 += 64) {
#pragma unroll
    for (int r = 0; r < 4; r++) {
      async_ld16(&kh[(size_t)(j0 + r * 16) * HDIM + ksrc], &Ks[r * 1024 + w * 512]);
      async_ld16(&vh[(size_t)(r * 16) * TOK + j0 + vsrc], &Vs[r * 1024 + w * 512]);
    }
    __syncthreads();

    // ---- S^T = K * Q^T : col = q = lane&15, row = key = quad*4+reg (+16*mi)
    floatx4 s[4][2];
#pragma unroll
    for (int mi = 0; mi < 4; mi++)
#pragma unroll
      for (int ni = 0; ni < 2; ni++) s[mi][ni] = ZV;
#pragma unroll
    for (int ks = 0; ks < 2; ks++)
#pragma unroll
      for (int mi = 0; mi < 4; mi++) {
        bf16x8 kf = *(const bf16x8*)&Ks[(mi * 16 + lrow) * 64 + (((ks * 4 + quad) ^ (lrow & 7)) * 8)];
#pragma unroll
        for (int ni = 0; ni < 2; ni++)
          s[mi][ni] = __builtin_amdgcn_mfma_f32_16x16x32_bf16(kf, qf[ni][ks], s[mi][ni], 0, 0, 0);
      }

    // ---- online softmax: 16 in-lane values + 2 max-shfls; l stays per-lane
    float alpha[2];
#pragma unroll
    for (int ni = 0; ni < 2; ni++) {
      float m0v = fmaxf(fmaxf(s[0][ni][0], s[0][ni][1]), fmaxf(s[0][ni][2], s[0][ni][3]));
      float m1v = fmaxf(fmaxf(s[1][ni][0], s[1][ni][1]), fmaxf(s[1][ni][2], s[1][ni][3]));
      float m2v = fmaxf(fmaxf(s[2][ni][0], s[2][ni][1]), fmaxf(s[2][ni][2], s[2][ni][3]));
      float m3v = fmaxf(fmaxf(s[3][ni][0], s[3][ni][1]), fmaxf(s[3][ni][2], s[3][ni][3]));
      float mx = fmaxf(fmaxf(m0v, m1v), fmaxf(m2v, m3v));
      mx = fmaxf(mx, __shfl_xor(mx, 16, 64));
      mx = fmaxf(mx, __shfl_xor(mx, 32, 64));
      const float mn = fmaxf(mst[ni], mx);
      alpha[ni] = __builtin_amdgcn_exp2f(mst[ni] - mn);
      mst[ni] = mn;
      float rs = 0.f;
#pragma unroll
      for (int mi = 0; mi < 4; mi++)
#pragma unroll
        for (int reg = 0; reg < 4; reg++) {
          float p = __builtin_amdgcn_exp2f(s[mi][ni][reg] - mn);
          s[mi][ni][reg] = p;
          rs += p;
        }
      lst[ni] = lst[ni] * alpha[ni] + rs;   // per-lane partial; butterfly at end
#pragma unroll
      for (int d = 0; d < 4; d++) o[d][ni] *= alpha[ni];
    }

    // ---- P^T -> per-wave Ps (C-layout -> B-layout), b64 writes
#pragma unroll
    for (int mi = 0; mi < 4; mi++)
#pragma unroll
      for (int ni = 0; ni < 2; ni++) {
        union { bf16_t b[4]; uint64_t u; } p;
#pragma unroll
        for (int reg = 0; reg < 4; reg++) p.b[reg] = (bf16_t)s[mi][ni][reg];
        *(uint64_t*)&Pw[(ni * 16 + lrow) * 72 + mi * 16 + quad * 4] = p.u;
      }

    // ---- O^T += V^T * P : A = V^T rows d, B = P cols q
#pragma unroll
    for (int ks = 0; ks < 2; ks++) {
      bf16x8 pf[2];
#pragma unroll
      for (int ni = 0; ni < 2; ni++)
        pf[ni] = *(const bf16x8*)&Pw[(ni * 16 + lrow) * 72 + ks * 32 + quad * 8];
#pragma unroll
      for (int d = 0; d < 4; d++) {
        bf16x8 vf = *(const bf16x8*)&Vs[(d * 16 + lrow) * 64 + (((ks * 4 + quad) ^ (lrow & 7)) * 8)];
#pragma unroll
        for (int ni = 0; ni < 2; ni++)
          o[d][ni] = __builtin_amdgcn_mfma_f32_16x16x32_bf16(vf, pf[ni], o[d][ni], 0, 0, 0);
      }
    }
    __syncthreads();
  }

  // ---- epilogue: finish l across quads; O^T regs = 4 consecutive d -> b64
#pragma unroll
  for (int ni = 0; ni < 2; ni++) {
    float l = lst[ni];
    l += __shfl_xor(l, 16, 64);
    l += __shfl_xor(l, 32, 64);
    const float inv = 1.0f / l;
    const int qrow = q0 + w * 32 + ni * 16 + lrow;
#pragma unroll
    for (int d = 0; d < 4; d++) {
      union { bf16_t b[4]; uint64_t u; } p;
#pragma unroll
      for (int reg = 0; reg < 4; reg++) p.b[reg] = (bf16_t)(o[d][ni][reg] * inv);
      *(uint64_t*)&ao[(size_t)qrow * DIM_ + h * HDIM + d * 16 + quad * 4] = p.u;
    }
  }
}

// ---------------- proj GEMM + bias (fp32 out), 64x128 tiles ----------------
__global__ __launch_bounds__(256) void k_proj(
    const bf16_t* __restrict__ A,   // [4096][1024]
    const bf16_t* __restrict__ Bt,  // [1024][1024]
    const float* __restrict__ bias, float* __restrict__ out) {
  constexpr int K = 1024, BK = 32;
  __shared__ bf16_t As[64 * BK] __attribute__((aligned(16)));
  __shared__ bf16_t Bs[128 * BK] __attribute__((aligned(16)));
  const int t = threadIdx.x;
  const int lane = t & 63, w = t >> 6;
  const int lrow = lane & 15, quad = lane >> 4;
  const int m0 = blockIdx.y * 64, n0 = blockIdx.x * 128;
  const int wm = (w >> 1) * 32, wn = (w & 1) * 64;

  const floatx4 ZV = {0.f, 0.f, 0.f, 0.f};
  floatx4 acc[2][4];
#pragma unroll
  for (int i = 0; i < 2; i++)
#pragma unroll
    for (int j = 0; j < 4; j++) acc[i][j] = ZV;

  for (int kt = 0; kt < K; kt += BK) {
    async_ld16(&A[(size_t)(m0 + (t >> 2)) * K + kt + (t & 3) * 8], &As[w * 512]);
#pragma unroll
    for (int r = 0; r < 2; r++) {
      int idx = r * 256 + t;
      async_ld16(&Bt[(size_t)(n0 + (idx >> 2)) * K + kt + (idx & 3) * 8],
                 &Bs[(r * 256 + w * 64) * 8]);
    }
    __syncthreads();
    bf16x8 af[2], bf[4];
#pragma unroll
    for (int i = 0; i < 2; i++)
      af[i] = *(const bf16x8*)&As[(wm + i * 16 + lrow) * BK + quad * 8];
#pragma unroll
    for (int i = 0; i < 4; i++)
      bf[i] = *(const bf16x8*)&Bs[(wn + i * 16 + lrow) * BK + quad * 8];
#pragma unroll
    for (int mi = 0; mi < 2; mi++)
#pragma unroll
      for (int ni = 0; ni < 4; ni++)
        acc[mi][ni] = __builtin_amdgcn_mfma_f32_16x16x32_bf16(af[mi], bf[ni], acc[mi][ni], 0, 0, 0);
    __syncthreads();
  }

  const int c0 = n0 + wn;
#pragma unroll
  for (int ni = 0; ni < 4; ni++) {
    float bv = bias[c0 + ni * 16 + lrow];
#pragma unroll
    for (int mi = 0; mi < 2; mi++)
#pragma unroll
      for (int reg = 0; reg < 4; reg++) {
        int r = m0 + wm + mi * 16 + quad * 4 + reg;
        out[(size_t)r * DIM_ + c0 + ni * 16 + lrow] = acc[mi][ni][reg] + bv;
      }
  }
}

extern "C" void kernel_launch(void* const* d_in, const int* in_sizes, int n_in,
                              void* d_out, int out_size, void* d_ws, size_t ws_size,
                              hipStream_t stream) {
  const float* x      = (const float*)d_in[0];
  const float* cs     = (const float*)d_in[1];
  const float* sn     = (const float*)d_in[2];
  const float* w_qkv  = (const float*)d_in[3];
  const float* b_qkv  = (const float*)d_in[4];
  const float* w_proj = (const float*)d_in[5];
  const float* b_proj = (const float*)d_in[6];
  float* out = (float*)d_out;

  char* ws = (char*)d_ws;
  bf16_t* xb     = (bf16_t*)(ws);
  bf16_t* wqkvT  = (bf16_t*)(ws + 8388608);
  bf16_t* wprojT = (bf16_t*)(ws + 14680064);
  bf16_t* qb     = (bf16_t*)(ws + 16777216);
  bf16_t* kb     = (bf16_t*)(ws + 25165824);
  bf16_t* vT     = (bf16_t*)(ws + 33554432);
  bf16_t* ao     = xb;  // x is dead after k_qkv; reuse its region

  k_cvt<<<dim3(4096), dim3(256), 0, stream>>>(x, xb, 1048576);
  k_tcvt<<<dim3(96, 32), dim3(256), 0, stream>>>(w_qkv, wqkvT, 1024, 3072);
  k_tcvt<<<dim3(32, 32), dim3(256), 0, stream>>>(w_proj, wprojT, 1024, 1024);
  k_qkv<<<dim3(24, 32), dim3(256), 0, stream>>>(xb, wqkvT, b_qkv, cs, sn, qb, kb, vT);
  k_attn<<<dim3(1024), dim3(128), 0, stream>>>(qb, kb, vT, ao);
  k_proj<<<dim3(8, 64), dim3(256), 0, stream>>>(ao, wprojT, b_proj, out);
}